// Round 8
// baseline (369.873 us; speedup 1.0000x reference)
//
#include <hip/hip_runtime.h>

// GCN: 3 layers, dims 64->64->64->32, N=100000 nodes, E=1600000 edges.
// Round 8:
//  - aggregate: lane-per-feature-pair (half-wave per node, M=64). NO cross-
//    lane reduction. R7 evidence: VALUBusy 47%, ~half the kernel was the
//    24-bpermute epilogue + tail of the wave-per-node slot design.
//  - fp16 activations (bufX): gemm input FETCH and aggregate WRITE halve.
//    All accumulation fp32; only storage is fp16.
//  - CSR build: ACHUNK 8192 (longer scatter runs, smaller offsets matrix),
//    scan_bsum merged into scan_final. 5 build dispatches, zero global atomics.

typedef __attribute__((ext_vector_type(8))) _Float16 half8;
typedef __attribute__((ext_vector_type(2))) _Float16 h2f;

static inline int cdiv(int a, int b) { return (a + b - 1) / b; }

#define ACHUNK 8192   // edges per pass-A block (256 thr x 32)
#define MAXNBK 512    // max buckets (N <= 131072)

// ---- pass A1: per-block bucket histogram -> counts_t[bucket*NBA + block]
__global__ void k_bucket_hist(const int* __restrict__ dst, int* __restrict__ counts_t,
                              int NBK, int NBA, int E) {
    __shared__ int cnt[MAXNBK];
    int t = threadIdx.x, b = blockIdx.x;
    for (int i = t; i < NBK; i += 256) cnt[i] = 0;
    __syncthreads();
    int e0 = b * ACHUNK;
#pragma unroll 8
    for (int j = 0; j < ACHUNK / 256; ++j) {
        int e = e0 + j * 256 + t;
        if (e < E) atomicAdd(&cnt[dst[e] >> 8], 1);
    }
    __syncthreads();
    for (int i = t; i < NBK; i += 256) counts_t[i * NBA + b] = cnt[i];
}

// ---- hierarchical exclusive scan over a[0..n): partial + (bsum-scan fused final)
#define SCAN_T 256
#define SCAN_V 4
#define SCAN_CHUNK 1024

__global__ void k_scan_partial(const int* __restrict__ a, int* __restrict__ bsum, int n) {
    __shared__ int red[SCAN_T];
    int t = threadIdx.x, b = blockIdx.x;
    int base = b * SCAN_CHUNK + t * SCAN_V;
    int s = 0;
#pragma unroll
    for (int j = 0; j < SCAN_V; ++j) { int i = base + j; if (i < n) s += a[i]; }
    red[t] = s;
    __syncthreads();
    for (int off = SCAN_T / 2; off > 0; off >>= 1) {
        if (t < off) red[t] += red[t + off];
        __syncthreads();
    }
    if (t == 0) bsum[b] = red[0];
}

// nb <= 256. Every block redundantly scans bsum in LDS, picks its base.
__global__ void k_scan_final(const int* __restrict__ a, const int* __restrict__ bsum,
                             int* __restrict__ out, int nb, int n) {
    __shared__ int sb[256];
    __shared__ int sh[SCAN_T];
    int t = threadIdx.x, bk = blockIdx.x;
    sb[t] = (t < nb) ? bsum[t] : 0;
    __syncthreads();
    for (int off = 1; off < 256; off <<= 1) {
        int u = (t >= off) ? sb[t - off] : 0;
        __syncthreads();
        sb[t] += u;
        __syncthreads();
    }
    int bbase = (bk == 0) ? 0 : sb[bk - 1];
    int base = bk * SCAN_CHUNK + t * SCAN_V;
    int v[SCAN_V];
    int s = 0;
#pragma unroll
    for (int j = 0; j < SCAN_V; ++j) {
        int i = base + j;
        v[j] = (i < n) ? a[i] : 0;
        s += v[j];
    }
    sh[t] = s;
    __syncthreads();
    for (int off = 1; off < SCAN_T; off <<= 1) {
        int u = (t >= off) ? sh[t - off] : 0;
        __syncthreads();
        sh[t] += u;
        __syncthreads();
    }
    int run = sh[t] - s + bbase;
#pragma unroll
    for (int j = 0; j < SCAN_V; ++j) {
        int i = base + j;
        if (i < n) { out[i] = run; run += v[j]; }
    }
}

// ---- pass A3: scatter edges into bucket regions via LDS cursors.
// packed word: src (24 bits) | (dst & 255) << 24. src < 2^17 fits.
__global__ void k_bucket_scatter(const int* __restrict__ src, const int* __restrict__ dst,
                                 const int* __restrict__ offsets, unsigned* __restrict__ bucketed,
                                 int NBK, int NBA, int E) {
    __shared__ int curs[MAXNBK];
    int t = threadIdx.x, b = blockIdx.x;
    for (int i = t; i < NBK; i += 256) curs[i] = offsets[i * NBA + b];
    __syncthreads();
    int e0 = b * ACHUNK;
#pragma unroll 8
    for (int j = 0; j < ACHUNK / 256; ++j) {
        int e = e0 + j * 256 + t;
        if (e < E) {
            int d = dst[e];
            int pos = atomicAdd(&curs[d >> 8], 1);
            bucketed[pos] = (unsigned)src[e] | ((unsigned)(d & 255) << 24);
        }
    }
}

// ---- pass B: one block per bucket. LDS hist over 256 nodes -> LDS scan ->
// emit csr_src (dst-sorted), row_start, dis.
__global__ void k_bucket_build(const unsigned* __restrict__ bucketed,
                               const int* __restrict__ offsets,
                               int* __restrict__ csr_src, int* __restrict__ row_start,
                               float* __restrict__ dis, int NBK, int NBA, int N, int E) {
    __shared__ int cnt[256];
    __shared__ int sc[256];
    int t = threadIdx.x, k = blockIdx.x;
    int base = offsets[k * NBA];
    int end = (k + 1 < NBK) ? offsets[(k + 1) * NBA] : E;
    cnt[t] = 0;
    __syncthreads();
    for (int i = base + t; i < end; i += 256)
        atomicAdd(&cnt[bucketed[i] >> 24], 1);
    __syncthreads();
    int c = cnt[t];
    sc[t] = c;
    __syncthreads();
    for (int off = 1; off < 256; off <<= 1) {
        int u = (t >= off) ? sc[t - off] : 0;
        __syncthreads();
        sc[t] += u;
        __syncthreads();
    }
    int excl = sc[t] - c;
    int node = k * 256 + t;
    if (node < N) {
        row_start[node] = base + excl;
        dis[node] = rsqrtf(1.0f + (float)c);
    }
    if (k == 0 && t == 0) row_start[N] = E;
    cnt[t] = base + excl;  // reuse as cursor
    __syncthreads();
    for (int i = base + t; i < end; i += 256) {
        unsigned w = bucketed[i];
        int pos = atomicAdd(&cnt[w >> 24], 1);
        csr_src[pos] = (int)(w & 0xFFFFFFu);
    }
}

// ---- GEMM core over fp32 LDS tiles; H = fp16((X@W) * dis[row]) ----
template <int K, int M>
__device__ inline void gemm_core(const float* Ws, const float* Xs,
                                 const float* __restrict__ dis,
                                 _Float16* __restrict__ H, int row0, int n) {
    constexpr int CPT = 8;
    constexpr int TPR = M / CPT;
    constexpr int KP = K + 1;
    int tid = threadIdx.x;
    int r = tid / TPR, c0 = (tid % TPR) * CPT;
    int row = row0 + r;
    if (row >= n) return;
    float4 a0 = make_float4(0.f, 0.f, 0.f, 0.f);
    float4 a1 = make_float4(0.f, 0.f, 0.f, 0.f);
#pragma unroll
    for (int k = 0; k < K; ++k) {
        float xv = Xs[r * KP + k];
        float4 w0 = ((const float4*)Ws)[(k * M + c0) / 4];
        float4 w1 = ((const float4*)Ws)[(k * M + c0) / 4 + 1];
        a0.x = fmaf(xv, w0.x, a0.x);
        a0.y = fmaf(xv, w0.y, a0.y);
        a0.z = fmaf(xv, w0.z, a0.z);
        a0.w = fmaf(xv, w0.w, a0.w);
        a1.x = fmaf(xv, w1.x, a1.x);
        a1.y = fmaf(xv, w1.y, a1.y);
        a1.z = fmaf(xv, w1.z, a1.z);
        a1.w = fmaf(xv, w1.w, a1.w);
    }
    float dn = dis[row];
    half8 hv;
    hv[0] = (_Float16)(a0.x * dn);
    hv[1] = (_Float16)(a0.y * dn);
    hv[2] = (_Float16)(a0.z * dn);
    hv[3] = (_Float16)(a0.w * dn);
    hv[4] = (_Float16)(a1.x * dn);
    hv[5] = (_Float16)(a1.y * dn);
    hv[6] = (_Float16)(a1.z * dn);
    hv[7] = (_Float16)(a1.w * dn);
    ((half8*)H)[(size_t)row * (M / CPT) + c0 / CPT] = hv;
}

// fp32-input GEMM (layer 1)
template <int K, int M>
__global__ void k_gemm_f(const float* __restrict__ X, const float* __restrict__ W,
                         const float* __restrict__ dis, _Float16* __restrict__ H, int n) {
    constexpr int TPR = M / 8;
    constexpr int ROWS = 256 / TPR;
    constexpr int KP = K + 1;
    __shared__ float Ws[K * M];
    __shared__ float Xs[ROWS * KP];
    int tid = threadIdx.x;
    for (int idx = tid; idx < K * M / 4; idx += 256)
        ((float4*)Ws)[idx] = ((const float4*)W)[idx];
    int row0 = blockIdx.x * ROWS;
    for (int idx = tid; idx < ROWS * (K / 4); idx += 256) {
        int r = idx / (K / 4), kq = idx % (K / 4);
        int row = row0 + r;
        float4 vv = (row < n) ? ((const float4*)X)[(size_t)row * (K / 4) + kq]
                              : make_float4(0.f, 0.f, 0.f, 0.f);
        Xs[r * KP + kq * 4 + 0] = vv.x;
        Xs[r * KP + kq * 4 + 1] = vv.y;
        Xs[r * KP + kq * 4 + 2] = vv.z;
        Xs[r * KP + kq * 4 + 3] = vv.w;
    }
    __syncthreads();
    gemm_core<K, M>(Ws, Xs, dis, H, row0, n);
}

// fp16-input GEMM (layers 2,3): converts to fp32 during LDS staging
template <int K, int M>
__global__ void k_gemm_h(const _Float16* __restrict__ X, const float* __restrict__ W,
                         const float* __restrict__ dis, _Float16* __restrict__ H, int n) {
    constexpr int TPR = M / 8;
    constexpr int ROWS = 256 / TPR;
    constexpr int KP = K + 1;
    __shared__ float Ws[K * M];
    __shared__ float Xs[ROWS * KP];
    int tid = threadIdx.x;
    for (int idx = tid; idx < K * M / 4; idx += 256)
        ((float4*)Ws)[idx] = ((const float4*)W)[idx];
    int row0 = blockIdx.x * ROWS;
    for (int idx = tid; idx < ROWS * (K / 8); idx += 256) {
        int r = idx / (K / 8), kq = idx % (K / 8);
        int row = row0 + r;
        if (row < n) {
            half8 v = ((const half8*)X)[(size_t)row * (K / 8) + kq];
#pragma unroll
            for (int j = 0; j < 8; ++j) Xs[r * KP + kq * 8 + j] = (float)v[j];
        } else {
#pragma unroll
            for (int j = 0; j < 8; ++j) Xs[r * KP + kq * 8 + j] = 0.f;
        }
    }
    __syncthreads();
    gemm_core<K, M>(Ws, Xs, dis, H, row0, n);
}

// ---- store helpers for aggregate epilogue
__device__ inline void store2(float* out, size_t idx, float rx, float ry) {
    ((float2*)out)[idx] = make_float2(rx, ry);
}
__device__ inline void store2(_Float16* out, size_t idx, float rx, float ry) {
    h2f v;
    v[0] = (_Float16)rx;
    v[1] = (_Float16)ry;
    ((h2f*)out)[idx] = v;
}

// ---- fused aggregate: lane-per-feature-pair, M/2 lanes per node, 64/(M/2)
// nodes per wave. No cross-lane reduction. fp32 accumulate.
// out[i] = dis[i]*(sum_e h'[src_e] + h'[i]) + b   (optional relu)
template <int M, bool RELU, typename OutT>
__global__ void k_aggregate(const _Float16* __restrict__ h, const float* __restrict__ dis,
                            const int* __restrict__ row_start, const int* __restrict__ csr_src,
                            const float* __restrict__ b, OutT* __restrict__ out, int n) {
    constexpr int LPN = M / 2;    // lanes per node (32 for M=64, 16 for M=32)
    constexpr int NPW = 64 / LPN; // nodes per wave
    int gtid = blockIdx.x * blockDim.x + threadIdx.x;
    int wave = gtid >> 6;
    int lane = threadIdx.x & 63;
    int sub = lane / LPN, fl = lane % LPN;
    int node = wave * NPW + sub;
    if (node >= n) return;
    int e = row_start[node], e1 = row_start[node + 1];
    const h2f* h2 = (const h2f*)h;
    float ax = 0.f, ay = 0.f, cx = 0.f, cy = 0.f;
    for (; e + 1 < e1; e += 2) {
        int s0 = csr_src[e];
        int s1 = csr_src[e + 1];
        h2f v0 = h2[(size_t)s0 * LPN + fl];
        h2f v1 = h2[(size_t)s1 * LPN + fl];
        ax += (float)v0[0];
        ay += (float)v0[1];
        cx += (float)v1[0];
        cy += (float)v1[1];
    }
    if (e < e1) {
        int s0 = csr_src[e];
        h2f v0 = h2[(size_t)s0 * LPN + fl];
        ax += (float)v0[0];
        ay += (float)v0[1];
    }
    ax += cx;
    ay += cy;
    float dn = dis[node];
    h2f hv = h2[(size_t)node * LPN + fl];
    float2 bb = ((const float2*)b)[fl];
    float rx = (ax + (float)hv[0]) * dn + bb.x;
    float ry = (ay + (float)hv[1]) * dn + bb.y;
    if (RELU) { rx = fmaxf(rx, 0.f); ry = fmaxf(ry, 0.f); }
    store2(out, (size_t)node * LPN + fl, rx, ry);
}

extern "C" void kernel_launch(void* const* d_in, const int* in_sizes, int n_in,
                              void* d_out, int out_size, void* d_ws, size_t ws_size,
                              hipStream_t stream) {
    const float* x   = (const float*)d_in[0];
    const int*   ei  = (const int*)d_in[1];
    const float* W1  = (const float*)d_in[2];
    const float* b1  = (const float*)d_in[3];
    const float* W2  = (const float*)d_in[4];
    const float* b2  = (const float*)d_in[5];
    const float* W3  = (const float*)d_in[6];
    const float* b3  = (const float*)d_in[7];
    float* out = (float*)d_out;

    const int N = in_sizes[0] / 64;
    const int E = in_sizes[1] / 2;
    const int* src = ei;
    const int* dst = ei + E;

    const int NBK = cdiv(N, 256);     // 391 buckets of 256 nodes
    const int NBA = cdiv(E, ACHUNK);  // 196 pass-A blocks
    const int nmat = NBK * NBA;       // 76636 scan elements

    // workspace layout
    const size_t Np = (size_t)((N + 63) / 64) * 64;
    char* p = (char*)d_ws;
    int*      counts_t = (int*)p;      p += (size_t)nmat * sizeof(int);
    int*      offsets  = (int*)p;      p += (size_t)nmat * sizeof(int);
    int*      bsum     = (int*)p;      p += 1024 * sizeof(int);
    int*      row_start= (int*)p;      p += (Np + 64) * sizeof(int);
    float*    dis      = (float*)p;    p += Np * sizeof(float);
    unsigned* bucketed = (unsigned*)p; p += (size_t)E * sizeof(unsigned);
    int*      csr_src  = (int*)p;      p += (size_t)E * sizeof(int);
    _Float16* bufH     = (_Float16*)p; p += Np * 64 * sizeof(_Float16);
    _Float16* bufX     = (_Float16*)p; p += Np * 64 * sizeof(_Float16);
    (void)ws_size;

    const int B = 256;
    const int nb = cdiv(nmat, SCAN_CHUNK);  // 75 <= 256

    // ---- CSR build: LDS counting sort, no global atomics ----
    k_bucket_hist<<<NBA, B, 0, stream>>>(dst, counts_t, NBK, NBA, E);
    k_scan_partial<<<nb, B, 0, stream>>>(counts_t, bsum, nmat);
    k_scan_final<<<nb, B, 0, stream>>>(counts_t, bsum, offsets, nb, nmat);
    k_bucket_scatter<<<NBA, B, 0, stream>>>(src, dst, offsets, bucketed, NBK, NBA, E);
    k_bucket_build<<<NBK, B, 0, stream>>>(bucketed, offsets, csr_src, row_start, dis,
                                          NBK, NBA, N, E);

    // aggregate grids: waves = cdiv(N, NPW); threads = waves*64
    const int blocks_a64 = cdiv(cdiv(N, 2) * 64, B);
    const int blocks_a32 = cdiv(cdiv(N, 4) * 64, B);

    // ---- layer 1: x(64) -> 64, relu ----
    k_gemm_f<64, 64><<<cdiv(N, 32), B, 0, stream>>>(x, W1, dis, bufH, N);
    k_aggregate<64, true, _Float16><<<blocks_a64, B, 0, stream>>>(
        bufH, dis, row_start, csr_src, b1, bufX, N);

    // ---- layer 2: 64 -> 64, relu ----
    k_gemm_h<64, 64><<<cdiv(N, 32), B, 0, stream>>>(bufX, W2, dis, bufH, N);
    k_aggregate<64, true, _Float16><<<blocks_a64, B, 0, stream>>>(
        bufH, dis, row_start, csr_src, b2, bufX, N);

    // ---- layer 3: 64 -> 32, no relu ----
    k_gemm_h<64, 32><<<cdiv(N, 64), B, 0, stream>>>(bufX, W3, dis, bufH, N);
    k_aggregate<32, false, float><<<blocks_a32, B, 0, stream>>>(
        bufH, dis, row_start, csr_src, b3, out, N);
}

// Round 9
// 342.153 us; speedup vs baseline: 1.0810x; 1.0810x over previous
//
#include <hip/hip_runtime.h>

// GCN: 3 layers, dims 64->64->64->32, N=100000 nodes, E=1600000 edges.
// Round 9: aggregate = lane-per-8-features (half8). R7 had good VMEM (16B/lane,
// 8 edges/wave-inst) but a 24-shuffle epilogue (VALUBusy 47%); R8 killed the
// shuffles but dropped to 4B/lane loads (4x VMEM insts -> 63us). This keeps
// 16B/lane AND zero shuffles: 8 lanes own one node's 64 feats (8 fp32 acc each),
// 8 nodes per wave; cost is only degree divergence across sub-nodes (~35%).
// fp16 storage everywhere between layers; fp32 accumulation throughout.
// CSR build: LDS two-level counting sort, zero global atomics (R6/R8).

typedef __attribute__((ext_vector_type(8))) _Float16 half8;

static inline int cdiv(int a, int b) { return (a + b - 1) / b; }

#define ACHUNK 8192   // edges per pass-A block (256 thr x 32)
#define MAXNBK 512    // max buckets (N <= 131072)

// ---- pass A1: per-block bucket histogram -> counts_t[bucket*NBA + block]
__global__ void k_bucket_hist(const int* __restrict__ dst, int* __restrict__ counts_t,
                              int NBK, int NBA, int E) {
    __shared__ int cnt[MAXNBK];
    int t = threadIdx.x, b = blockIdx.x;
    for (int i = t; i < NBK; i += 256) cnt[i] = 0;
    __syncthreads();
    int e0 = b * ACHUNK;
#pragma unroll 8
    for (int j = 0; j < ACHUNK / 256; ++j) {
        int e = e0 + j * 256 + t;
        if (e < E) atomicAdd(&cnt[dst[e] >> 8], 1);
    }
    __syncthreads();
    for (int i = t; i < NBK; i += 256) counts_t[i * NBA + b] = cnt[i];
}

// ---- hierarchical exclusive scan over a[0..n): partial + (bsum-scan fused final)
#define SCAN_T 256
#define SCAN_V 4
#define SCAN_CHUNK 1024

__global__ void k_scan_partial(const int* __restrict__ a, int* __restrict__ bsum, int n) {
    __shared__ int red[SCAN_T];
    int t = threadIdx.x, b = blockIdx.x;
    int base = b * SCAN_CHUNK + t * SCAN_V;
    int s = 0;
#pragma unroll
    for (int j = 0; j < SCAN_V; ++j) { int i = base + j; if (i < n) s += a[i]; }
    red[t] = s;
    __syncthreads();
    for (int off = SCAN_T / 2; off > 0; off >>= 1) {
        if (t < off) red[t] += red[t + off];
        __syncthreads();
    }
    if (t == 0) bsum[b] = red[0];
}

// nb <= 256. Every block redundantly scans bsum in LDS, picks its base.
__global__ void k_scan_final(const int* __restrict__ a, const int* __restrict__ bsum,
                             int* __restrict__ out, int nb, int n) {
    __shared__ int sb[256];
    __shared__ int sh[SCAN_T];
    int t = threadIdx.x, bk = blockIdx.x;
    sb[t] = (t < nb) ? bsum[t] : 0;
    __syncthreads();
    for (int off = 1; off < 256; off <<= 1) {
        int u = (t >= off) ? sb[t - off] : 0;
        __syncthreads();
        sb[t] += u;
        __syncthreads();
    }
    int bbase = (bk == 0) ? 0 : sb[bk - 1];
    int base = bk * SCAN_CHUNK + t * SCAN_V;
    int v[SCAN_V];
    int s = 0;
#pragma unroll
    for (int j = 0; j < SCAN_V; ++j) {
        int i = base + j;
        v[j] = (i < n) ? a[i] : 0;
        s += v[j];
    }
    sh[t] = s;
    __syncthreads();
    for (int off = 1; off < SCAN_T; off <<= 1) {
        int u = (t >= off) ? sh[t - off] : 0;
        __syncthreads();
        sh[t] += u;
        __syncthreads();
    }
    int run = sh[t] - s + bbase;
#pragma unroll
    for (int j = 0; j < SCAN_V; ++j) {
        int i = base + j;
        if (i < n) { out[i] = run; run += v[j]; }
    }
}

// ---- pass A3: scatter edges into bucket regions via LDS cursors.
// packed word: src (24 bits) | (dst & 255) << 24. src < 2^17 fits.
__global__ void k_bucket_scatter(const int* __restrict__ src, const int* __restrict__ dst,
                                 const int* __restrict__ offsets, unsigned* __restrict__ bucketed,
                                 int NBK, int NBA, int E) {
    __shared__ int curs[MAXNBK];
    int t = threadIdx.x, b = blockIdx.x;
    for (int i = t; i < NBK; i += 256) curs[i] = offsets[i * NBA + b];
    __syncthreads();
    int e0 = b * ACHUNK;
#pragma unroll 8
    for (int j = 0; j < ACHUNK / 256; ++j) {
        int e = e0 + j * 256 + t;
        if (e < E) {
            int d = dst[e];
            int pos = atomicAdd(&curs[d >> 8], 1);
            bucketed[pos] = (unsigned)src[e] | ((unsigned)(d & 255) << 24);
        }
    }
}

// ---- pass B: one block per bucket. LDS hist over 256 nodes -> LDS scan ->
// emit csr_src (dst-sorted), row_start, dis.
__global__ void k_bucket_build(const unsigned* __restrict__ bucketed,
                               const int* __restrict__ offsets,
                               int* __restrict__ csr_src, int* __restrict__ row_start,
                               float* __restrict__ dis, int NBK, int NBA, int N, int E) {
    __shared__ int cnt[256];
    __shared__ int sc[256];
    int t = threadIdx.x, k = blockIdx.x;
    int base = offsets[k * NBA];
    int end = (k + 1 < NBK) ? offsets[(k + 1) * NBA] : E;
    cnt[t] = 0;
    __syncthreads();
    for (int i = base + t; i < end; i += 256)
        atomicAdd(&cnt[bucketed[i] >> 24], 1);
    __syncthreads();
    int c = cnt[t];
    sc[t] = c;
    __syncthreads();
    for (int off = 1; off < 256; off <<= 1) {
        int u = (t >= off) ? sc[t - off] : 0;
        __syncthreads();
        sc[t] += u;
        __syncthreads();
    }
    int excl = sc[t] - c;
    int node = k * 256 + t;
    if (node < N) {
        row_start[node] = base + excl;
        dis[node] = rsqrtf(1.0f + (float)c);
    }
    if (k == 0 && t == 0) row_start[N] = E;
    cnt[t] = base + excl;  // reuse as cursor
    __syncthreads();
    for (int i = base + t; i < end; i += 256) {
        unsigned w = bucketed[i];
        int pos = atomicAdd(&cnt[w >> 24], 1);
        csr_src[pos] = (int)(w & 0xFFFFFFu);
    }
}

// ---- GEMM core over fp32 LDS tiles; H = fp16((X@W) * dis[row]) ----
template <int K, int M>
__device__ inline void gemm_core(const float* Ws, const float* Xs,
                                 const float* __restrict__ dis,
                                 _Float16* __restrict__ H, int row0, int n) {
    constexpr int CPT = 8;
    constexpr int TPR = M / CPT;
    constexpr int KP = K + 1;
    int tid = threadIdx.x;
    int r = tid / TPR, c0 = (tid % TPR) * CPT;
    int row = row0 + r;
    if (row >= n) return;
    float4 a0 = make_float4(0.f, 0.f, 0.f, 0.f);
    float4 a1 = make_float4(0.f, 0.f, 0.f, 0.f);
#pragma unroll
    for (int k = 0; k < K; ++k) {
        float xv = Xs[r * KP + k];
        float4 w0 = ((const float4*)Ws)[(k * M + c0) / 4];
        float4 w1 = ((const float4*)Ws)[(k * M + c0) / 4 + 1];
        a0.x = fmaf(xv, w0.x, a0.x);
        a0.y = fmaf(xv, w0.y, a0.y);
        a0.z = fmaf(xv, w0.z, a0.z);
        a0.w = fmaf(xv, w0.w, a0.w);
        a1.x = fmaf(xv, w1.x, a1.x);
        a1.y = fmaf(xv, w1.y, a1.y);
        a1.z = fmaf(xv, w1.z, a1.z);
        a1.w = fmaf(xv, w1.w, a1.w);
    }
    float dn = dis[row];
    half8 hv;
    hv[0] = (_Float16)(a0.x * dn);
    hv[1] = (_Float16)(a0.y * dn);
    hv[2] = (_Float16)(a0.z * dn);
    hv[3] = (_Float16)(a0.w * dn);
    hv[4] = (_Float16)(a1.x * dn);
    hv[5] = (_Float16)(a1.y * dn);
    hv[6] = (_Float16)(a1.z * dn);
    hv[7] = (_Float16)(a1.w * dn);
    ((half8*)H)[(size_t)row * (M / CPT) + c0 / CPT] = hv;
}

// fp32-input GEMM (layer 1)
template <int K, int M>
__global__ void k_gemm_f(const float* __restrict__ X, const float* __restrict__ W,
                         const float* __restrict__ dis, _Float16* __restrict__ H, int n) {
    constexpr int TPR = M / 8;
    constexpr int ROWS = 256 / TPR;
    constexpr int KP = K + 1;
    __shared__ float Ws[K * M];
    __shared__ float Xs[ROWS * KP];
    int tid = threadIdx.x;
    for (int idx = tid; idx < K * M / 4; idx += 256)
        ((float4*)Ws)[idx] = ((const float4*)W)[idx];
    int row0 = blockIdx.x * ROWS;
    for (int idx = tid; idx < ROWS * (K / 4); idx += 256) {
        int r = idx / (K / 4), kq = idx % (K / 4);
        int row = row0 + r;
        float4 vv = (row < n) ? ((const float4*)X)[(size_t)row * (K / 4) + kq]
                              : make_float4(0.f, 0.f, 0.f, 0.f);
        Xs[r * KP + kq * 4 + 0] = vv.x;
        Xs[r * KP + kq * 4 + 1] = vv.y;
        Xs[r * KP + kq * 4 + 2] = vv.z;
        Xs[r * KP + kq * 4 + 3] = vv.w;
    }
    __syncthreads();
    gemm_core<K, M>(Ws, Xs, dis, H, row0, n);
}

// fp16-input GEMM (layers 2,3): converts to fp32 during LDS staging
template <int K, int M>
__global__ void k_gemm_h(const _Float16* __restrict__ X, const float* __restrict__ W,
                         const float* __restrict__ dis, _Float16* __restrict__ H, int n) {
    constexpr int TPR = M / 8;
    constexpr int ROWS = 256 / TPR;
    constexpr int KP = K + 1;
    __shared__ float Ws[K * M];
    __shared__ float Xs[ROWS * KP];
    int tid = threadIdx.x;
    for (int idx = tid; idx < K * M / 4; idx += 256)
        ((float4*)Ws)[idx] = ((const float4*)W)[idx];
    int row0 = blockIdx.x * ROWS;
    for (int idx = tid; idx < ROWS * (K / 8); idx += 256) {
        int r = idx / (K / 8), kq = idx % (K / 8);
        int row = row0 + r;
        if (row < n) {
            half8 v = ((const half8*)X)[(size_t)row * (K / 8) + kq];
#pragma unroll
            for (int j = 0; j < 8; ++j) Xs[r * KP + kq * 8 + j] = (float)v[j];
        } else {
#pragma unroll
            for (int j = 0; j < 8; ++j) Xs[r * KP + kq * 8 + j] = 0.f;
        }
    }
    __syncthreads();
    gemm_core<K, M>(Ws, Xs, dis, H, row0, n);
}

// ---- store helpers for aggregate epilogue (8 floats per lane)
__device__ inline void store8(float* out, int node, int fl, int LPN, const float* r) {
    float4* op = (float4*)(out + ((size_t)node * LPN + fl) * 8);
    op[0] = make_float4(r[0], r[1], r[2], r[3]);
    op[1] = make_float4(r[4], r[5], r[6], r[7]);
}
__device__ inline void store8(_Float16* out, int node, int fl, int LPN, const float* r) {
    half8 v;
#pragma unroll
    for (int j = 0; j < 8; ++j) v[j] = (_Float16)r[j];
    ((half8*)out)[(size_t)node * LPN + fl] = v;
}

// ---- fused aggregate: lane-per-8-features. LPN = M/8 lanes per node,
// NPW = 64/LPN nodes per wave. half8 (16B) loads, zero cross-lane reduction.
// out[i] = dis[i]*(sum_e h'[src_e] + h'[i]) + b   (optional relu)
template <int M, bool RELU, typename OutT>
__global__ void k_aggregate(const _Float16* __restrict__ h, const float* __restrict__ dis,
                            const int* __restrict__ row_start, const int* __restrict__ csr_src,
                            const float* __restrict__ b, OutT* __restrict__ out, int n) {
    constexpr int LPN = M / 8;    // lanes per node (8 for M=64, 4 for M=32)
    constexpr int NPW = 64 / LPN; // nodes per wave (8, 16)
    int gtid = blockIdx.x * blockDim.x + threadIdx.x;
    int wave = gtid >> 6;
    int lane = threadIdx.x & 63;
    int sub = lane / LPN, fl = lane % LPN;
    int node = wave * NPW + sub;
    if (node >= n) return;
    const half8* h8 = (const half8*)h;
    float acc[8];
#pragma unroll
    for (int j = 0; j < 8; ++j) acc[j] = 0.f;
    int e = row_start[node], e1 = row_start[node + 1];
    for (; e + 1 < e1; e += 2) {
        int s0 = csr_src[e];
        int s1 = csr_src[e + 1];
        half8 v0 = h8[(size_t)s0 * LPN + fl];
        half8 v1 = h8[(size_t)s1 * LPN + fl];
#pragma unroll
        for (int j = 0; j < 8; ++j) acc[j] += (float)v0[j] + (float)v1[j];
    }
    if (e < e1) {
        int s0 = csr_src[e];
        half8 v0 = h8[(size_t)s0 * LPN + fl];
#pragma unroll
        for (int j = 0; j < 8; ++j) acc[j] += (float)v0[j];
    }
    float dn = dis[node];
    half8 hv = h8[(size_t)node * LPN + fl];
    float4 b0 = ((const float4*)b)[fl * 2];
    float4 b1 = ((const float4*)b)[fl * 2 + 1];
    float r[8];
    r[0] = (acc[0] + (float)hv[0]) * dn + b0.x;
    r[1] = (acc[1] + (float)hv[1]) * dn + b0.y;
    r[2] = (acc[2] + (float)hv[2]) * dn + b0.z;
    r[3] = (acc[3] + (float)hv[3]) * dn + b0.w;
    r[4] = (acc[4] + (float)hv[4]) * dn + b1.x;
    r[5] = (acc[5] + (float)hv[5]) * dn + b1.y;
    r[6] = (acc[6] + (float)hv[6]) * dn + b1.z;
    r[7] = (acc[7] + (float)hv[7]) * dn + b1.w;
    if (RELU) {
#pragma unroll
        for (int j = 0; j < 8; ++j) r[j] = fmaxf(r[j], 0.f);
    }
    store8(out, node, fl, LPN, r);
}

extern "C" void kernel_launch(void* const* d_in, const int* in_sizes, int n_in,
                              void* d_out, int out_size, void* d_ws, size_t ws_size,
                              hipStream_t stream) {
    const float* x   = (const float*)d_in[0];
    const int*   ei  = (const int*)d_in[1];
    const float* W1  = (const float*)d_in[2];
    const float* b1  = (const float*)d_in[3];
    const float* W2  = (const float*)d_in[4];
    const float* b2  = (const float*)d_in[5];
    const float* W3  = (const float*)d_in[6];
    const float* b3  = (const float*)d_in[7];
    float* out = (float*)d_out;

    const int N = in_sizes[0] / 64;
    const int E = in_sizes[1] / 2;
    const int* src = ei;
    const int* dst = ei + E;

    const int NBK = cdiv(N, 256);     // 391 buckets of 256 nodes
    const int NBA = cdiv(E, ACHUNK);  // 196 pass-A blocks
    const int nmat = NBK * NBA;       // 76636 scan elements

    // workspace layout
    const size_t Np = (size_t)((N + 63) / 64) * 64;
    char* p = (char*)d_ws;
    int*      counts_t = (int*)p;      p += (size_t)nmat * sizeof(int);
    int*      offsets  = (int*)p;      p += (size_t)nmat * sizeof(int);
    int*      bsum     = (int*)p;      p += 1024 * sizeof(int);
    int*      row_start= (int*)p;      p += (Np + 64) * sizeof(int);
    float*    dis      = (float*)p;    p += Np * sizeof(float);
    unsigned* bucketed = (unsigned*)p; p += (size_t)E * sizeof(unsigned);
    int*      csr_src  = (int*)p;      p += (size_t)E * sizeof(int);
    _Float16* bufH     = (_Float16*)p; p += Np * 64 * sizeof(_Float16);
    _Float16* bufX     = (_Float16*)p; p += Np * 64 * sizeof(_Float16);
    (void)ws_size;

    const int B = 256;
    const int nb = cdiv(nmat, SCAN_CHUNK);  // 75 <= 256

    // ---- CSR build: LDS counting sort, no global atomics ----
    k_bucket_hist<<<NBA, B, 0, stream>>>(dst, counts_t, NBK, NBA, E);
    k_scan_partial<<<nb, B, 0, stream>>>(counts_t, bsum, nmat);
    k_scan_final<<<nb, B, 0, stream>>>(counts_t, bsum, offsets, nb, nmat);
    k_bucket_scatter<<<NBA, B, 0, stream>>>(src, dst, offsets, bucketed, NBK, NBA, E);
    k_bucket_build<<<NBK, B, 0, stream>>>(bucketed, offsets, csr_src, row_start, dis,
                                          NBK, NBA, N, E);

    // aggregate grids: one wave per NPW nodes
    const int blocks_a64 = cdiv(cdiv(N, 8) * 64, B);
    const int blocks_a32 = cdiv(cdiv(N, 16) * 64, B);

    // ---- layer 1: x(64) -> 64, relu ----
    k_gemm_f<64, 64><<<cdiv(N, 32), B, 0, stream>>>(x, W1, dis, bufH, N);
    k_aggregate<64, true, _Float16><<<blocks_a64, B, 0, stream>>>(
        bufH, dis, row_start, csr_src, b1, bufX, N);

    // ---- layer 2: 64 -> 64, relu ----
    k_gemm_h<64, 64><<<cdiv(N, 32), B, 0, stream>>>(bufX, W2, dis, bufH, N);
    k_aggregate<64, true, _Float16><<<blocks_a64, B, 0, stream>>>(
        bufH, dis, row_start, csr_src, b2, bufX, N);

    // ---- layer 3: 64 -> 32, no relu ----
    k_gemm_h<64, 32><<<cdiv(N, 64), B, 0, stream>>>(bufX, W3, dis, bufH, N);
    k_aggregate<32, false, float><<<blocks_a32, B, 0, stream>>>(
        bufH, dis, row_start, csr_src, b3, out, N);
}

// Round 10
// 299.332 us; speedup vs baseline: 1.2357x; 1.1431x over previous
//
#include <hip/hip_runtime.h>

// GCN: 3 layers, dims 64->64->64->32, N=100000 nodes, E=1600000 edges.
// Round 10:
//  - fuse aggregate_i + gemm_{i+1} into one kernel (agg 32 nodes/block ->
//    fp32 LDS -> blockwise GEMM). Deletes X2/X3 global round-trips (~51MB)
//    and 2 dispatches. R9 evidence: ~130us of small-kernel + gap overhead.
//  - 4-edge unroll in aggregates (4 outstanding gathers/lane): R7 vs R9 both
//    plateau at 53.5us/159MB -> probe whether gather is MLP- or ceiling-bound.
//  - aggregate layout: lane-per-8-features (R9), fp16 storage, fp32 accum.
// CSR build: LDS two-level counting sort, zero global atomics (R6).

typedef __attribute__((ext_vector_type(8))) _Float16 half8;

static inline int cdiv(int a, int b) { return (a + b - 1) / b; }

#define ACHUNK 8192   // edges per pass-A block (256 thr x 32)
#define MAXNBK 512    // max buckets (N <= 131072)

// ---- pass A1: per-block bucket histogram -> counts_t[bucket*NBA + block]
__global__ void k_bucket_hist(const int* __restrict__ dst, int* __restrict__ counts_t,
                              int NBK, int NBA, int E) {
    __shared__ int cnt[MAXNBK];
    int t = threadIdx.x, b = blockIdx.x;
    for (int i = t; i < NBK; i += 256) cnt[i] = 0;
    __syncthreads();
    int e0 = b * ACHUNK;
#pragma unroll 8
    for (int j = 0; j < ACHUNK / 256; ++j) {
        int e = e0 + j * 256 + t;
        if (e < E) atomicAdd(&cnt[dst[e] >> 8], 1);
    }
    __syncthreads();
    for (int i = t; i < NBK; i += 256) counts_t[i * NBA + b] = cnt[i];
}

// ---- hierarchical exclusive scan over a[0..n): partial + (bsum-scan fused final)
#define SCAN_T 256
#define SCAN_V 4
#define SCAN_CHUNK 1024

__global__ void k_scan_partial(const int* __restrict__ a, int* __restrict__ bsum, int n) {
    __shared__ int red[SCAN_T];
    int t = threadIdx.x, b = blockIdx.x;
    int base = b * SCAN_CHUNK + t * SCAN_V;
    int s = 0;
#pragma unroll
    for (int j = 0; j < SCAN_V; ++j) { int i = base + j; if (i < n) s += a[i]; }
    red[t] = s;
    __syncthreads();
    for (int off = SCAN_T / 2; off > 0; off >>= 1) {
        if (t < off) red[t] += red[t + off];
        __syncthreads();
    }
    if (t == 0) bsum[b] = red[0];
}

// nb <= 256. Every block redundantly scans bsum in LDS, picks its base.
__global__ void k_scan_final(const int* __restrict__ a, const int* __restrict__ bsum,
                             int* __restrict__ out, int nb, int n) {
    __shared__ int sb[256];
    __shared__ int sh[SCAN_T];
    int t = threadIdx.x, bk = blockIdx.x;
    sb[t] = (t < nb) ? bsum[t] : 0;
    __syncthreads();
    for (int off = 1; off < 256; off <<= 1) {
        int u = (t >= off) ? sb[t - off] : 0;
        __syncthreads();
        sb[t] += u;
        __syncthreads();
    }
    int bbase = (bk == 0) ? 0 : sb[bk - 1];
    int base = bk * SCAN_CHUNK + t * SCAN_V;
    int v[SCAN_V];
    int s = 0;
#pragma unroll
    for (int j = 0; j < SCAN_V; ++j) {
        int i = base + j;
        v[j] = (i < n) ? a[i] : 0;
        s += v[j];
    }
    sh[t] = s;
    __syncthreads();
    for (int off = 1; off < SCAN_T; off <<= 1) {
        int u = (t >= off) ? sh[t - off] : 0;
        __syncthreads();
        sh[t] += u;
        __syncthreads();
    }
    int run = sh[t] - s + bbase;
#pragma unroll
    for (int j = 0; j < SCAN_V; ++j) {
        int i = base + j;
        if (i < n) { out[i] = run; run += v[j]; }
    }
}

// ---- pass A3: scatter edges into bucket regions via LDS cursors.
// packed word: src (24 bits) | (dst & 255) << 24.
__global__ void k_bucket_scatter(const int* __restrict__ src, const int* __restrict__ dst,
                                 const int* __restrict__ offsets, unsigned* __restrict__ bucketed,
                                 int NBK, int NBA, int E) {
    __shared__ int curs[MAXNBK];
    int t = threadIdx.x, b = blockIdx.x;
    for (int i = t; i < NBK; i += 256) curs[i] = offsets[i * NBA + b];
    __syncthreads();
    int e0 = b * ACHUNK;
#pragma unroll 8
    for (int j = 0; j < ACHUNK / 256; ++j) {
        int e = e0 + j * 256 + t;
        if (e < E) {
            int d = dst[e];
            int pos = atomicAdd(&curs[d >> 8], 1);
            bucketed[pos] = (unsigned)src[e] | ((unsigned)(d & 255) << 24);
        }
    }
}

// ---- pass B: one block per bucket. LDS hist over 256 nodes -> LDS scan ->
// emit csr_src (dst-sorted), row_start, dis.
__global__ void k_bucket_build(const unsigned* __restrict__ bucketed,
                               const int* __restrict__ offsets,
                               int* __restrict__ csr_src, int* __restrict__ row_start,
                               float* __restrict__ dis, int NBK, int NBA, int N, int E) {
    __shared__ int cnt[256];
    __shared__ int sc[256];
    int t = threadIdx.x, k = blockIdx.x;
    int base = offsets[k * NBA];
    int end = (k + 1 < NBK) ? offsets[(k + 1) * NBA] : E;
    cnt[t] = 0;
    __syncthreads();
    for (int i = base + t; i < end; i += 256)
        atomicAdd(&cnt[bucketed[i] >> 24], 1);
    __syncthreads();
    int c = cnt[t];
    sc[t] = c;
    __syncthreads();
    for (int off = 1; off < 256; off <<= 1) {
        int u = (t >= off) ? sc[t - off] : 0;
        __syncthreads();
        sc[t] += u;
        __syncthreads();
    }
    int excl = sc[t] - c;
    int node = k * 256 + t;
    if (node < N) {
        row_start[node] = base + excl;
        dis[node] = rsqrtf(1.0f + (float)c);
    }
    if (k == 0 && t == 0) row_start[N] = E;
    cnt[t] = base + excl;  // reuse as cursor
    __syncthreads();
    for (int i = base + t; i < end; i += 256) {
        unsigned w = bucketed[i];
        int pos = atomicAdd(&cnt[w >> 24], 1);
        csr_src[pos] = (int)(w & 0xFFFFFFu);
    }
}

// ---- fp32-input GEMM (layer 1): H = fp16((X@W) * dis[row]), 8 outs/thread
template <int K, int M>
__global__ void k_gemm_f(const float* __restrict__ X, const float* __restrict__ W,
                         const float* __restrict__ dis, _Float16* __restrict__ H, int n) {
    constexpr int TPR = M / 8;
    constexpr int ROWS = 256 / TPR;
    constexpr int KP = K + 1;
    __shared__ float Ws[K * M];
    __shared__ float Xs[ROWS * KP];
    int tid = threadIdx.x;
    for (int idx = tid; idx < K * M / 4; idx += 256)
        ((float4*)Ws)[idx] = ((const float4*)W)[idx];
    int row0 = blockIdx.x * ROWS;
    for (int idx = tid; idx < ROWS * (K / 4); idx += 256) {
        int r = idx / (K / 4), kq = idx % (K / 4);
        int row = row0 + r;
        float4 vv = (row < n) ? ((const float4*)X)[(size_t)row * (K / 4) + kq]
                              : make_float4(0.f, 0.f, 0.f, 0.f);
        Xs[r * KP + kq * 4 + 0] = vv.x;
        Xs[r * KP + kq * 4 + 1] = vv.y;
        Xs[r * KP + kq * 4 + 2] = vv.z;
        Xs[r * KP + kq * 4 + 3] = vv.w;
    }
    __syncthreads();
    int r = tid / TPR, c0 = (tid % TPR) * 8;
    int row = row0 + r;
    if (row >= n) return;
    float4 a0 = make_float4(0.f, 0.f, 0.f, 0.f);
    float4 a1 = make_float4(0.f, 0.f, 0.f, 0.f);
#pragma unroll
    for (int k = 0; k < K; ++k) {
        float xv = Xs[r * KP + k];
        float4 w0 = ((const float4*)Ws)[(k * M + c0) / 4];
        float4 w1 = ((const float4*)Ws)[(k * M + c0) / 4 + 1];
        a0.x = fmaf(xv, w0.x, a0.x);
        a0.y = fmaf(xv, w0.y, a0.y);
        a0.z = fmaf(xv, w0.z, a0.z);
        a0.w = fmaf(xv, w0.w, a0.w);
        a1.x = fmaf(xv, w1.x, a1.x);
        a1.y = fmaf(xv, w1.y, a1.y);
        a1.z = fmaf(xv, w1.z, a1.z);
        a1.w = fmaf(xv, w1.w, a1.w);
    }
    float dn = dis[row];
    half8 hv;
    hv[0] = (_Float16)(a0.x * dn);
    hv[1] = (_Float16)(a0.y * dn);
    hv[2] = (_Float16)(a0.z * dn);
    hv[3] = (_Float16)(a0.w * dn);
    hv[4] = (_Float16)(a1.x * dn);
    hv[5] = (_Float16)(a1.y * dn);
    hv[6] = (_Float16)(a1.z * dn);
    hv[7] = (_Float16)(a1.w * dn);
    ((half8*)H)[(size_t)row * (M / 8) + c0 / 8] = hv;
}

// ---- FUSED: aggregate(64) [+relu] -> LDS -> GEMM(64 x MOUT) -> h' fp16.
// 32 nodes per block (4 waves x 8 nodes, lane-per-8-features, 4-edge unroll).
// X_next[i] = relu(dis[i]*(sum_e h[src_e] + h[i]) + bagg)   (in LDS)
// H[i]      = fp16((X_next[i] @ W) * dis[i])
template <int MOUT>
__global__ void k_fused_agg_gemm(const _Float16* __restrict__ h, const float* __restrict__ dis,
                                 const int* __restrict__ row_start, const int* __restrict__ csr_src,
                                 const float* __restrict__ bagg, const float* __restrict__ W,
                                 _Float16* __restrict__ H, int n) {
    constexpr int K = 64, KP = K + 1;
    __shared__ float Ws[K * MOUT];
    __shared__ float Xs[32 * KP];
    int tid = threadIdx.x;
    // stage W (16KB for MOUT=64, 8KB for 32) -- L2-hot after first blocks
    for (int idx = tid; idx < K * MOUT / 4; idx += 256)
        ((float4*)Ws)[idx] = ((const float4*)W)[idx];

    // ---- aggregate phase ----
    int wave = tid >> 6, lane = tid & 63;
    int sub = lane >> 3, fl = lane & 7;
    int node0 = blockIdx.x * 32;
    int node = node0 + wave * 8 + sub;
    if (node < n) {
        const half8* h8 = (const half8*)h;
        float acc[8];
#pragma unroll
        for (int j = 0; j < 8; ++j) acc[j] = 0.f;
        int e = row_start[node], e1 = row_start[node + 1];
        for (; e + 3 < e1; e += 4) {
            int s0 = csr_src[e], s1 = csr_src[e + 1];
            int s2 = csr_src[e + 2], s3 = csr_src[e + 3];
            half8 v0 = h8[(size_t)s0 * 8 + fl];
            half8 v1 = h8[(size_t)s1 * 8 + fl];
            half8 v2 = h8[(size_t)s2 * 8 + fl];
            half8 v3 = h8[(size_t)s3 * 8 + fl];
#pragma unroll
            for (int j = 0; j < 8; ++j)
                acc[j] += ((float)v0[j] + (float)v1[j]) + ((float)v2[j] + (float)v3[j]);
        }
        for (; e < e1; ++e) {
            int s0 = csr_src[e];
            half8 v0 = h8[(size_t)s0 * 8 + fl];
#pragma unroll
            for (int j = 0; j < 8; ++j) acc[j] += (float)v0[j];
        }
        float dn = dis[node];
        half8 hv = h8[(size_t)node * 8 + fl];
        float4 b0 = ((const float4*)bagg)[fl * 2];
        float4 b1 = ((const float4*)bagg)[fl * 2 + 1];
        int rrow = wave * 8 + sub;
        float* xp = &Xs[rrow * KP + fl * 8];
        xp[0] = fmaxf((acc[0] + (float)hv[0]) * dn + b0.x, 0.f);
        xp[1] = fmaxf((acc[1] + (float)hv[1]) * dn + b0.y, 0.f);
        xp[2] = fmaxf((acc[2] + (float)hv[2]) * dn + b0.z, 0.f);
        xp[3] = fmaxf((acc[3] + (float)hv[3]) * dn + b0.w, 0.f);
        xp[4] = fmaxf((acc[4] + (float)hv[4]) * dn + b1.x, 0.f);
        xp[5] = fmaxf((acc[5] + (float)hv[5]) * dn + b1.y, 0.f);
        xp[6] = fmaxf((acc[6] + (float)hv[6]) * dn + b1.z, 0.f);
        xp[7] = fmaxf((acc[7] + (float)hv[7]) * dn + b1.w, 0.f);
    }
    __syncthreads();

    // ---- gemm phase: 32 rows x MOUT cols, 8 cols/thread ----
    constexpr int TPR = MOUT / 8;
    int r = tid / TPR, c0 = (tid % TPR) * 8;
    int row = node0 + r;
    if (r >= 32 || row >= n) return;
    float4 a0 = make_float4(0.f, 0.f, 0.f, 0.f);
    float4 a1 = make_float4(0.f, 0.f, 0.f, 0.f);
#pragma unroll
    for (int k = 0; k < K; ++k) {
        float xv = Xs[r * KP + k];
        float4 w0 = ((const float4*)Ws)[(k * MOUT + c0) / 4];
        float4 w1 = ((const float4*)Ws)[(k * MOUT + c0) / 4 + 1];
        a0.x = fmaf(xv, w0.x, a0.x);
        a0.y = fmaf(xv, w0.y, a0.y);
        a0.z = fmaf(xv, w0.z, a0.z);
        a0.w = fmaf(xv, w0.w, a0.w);
        a1.x = fmaf(xv, w1.x, a1.x);
        a1.y = fmaf(xv, w1.y, a1.y);
        a1.z = fmaf(xv, w1.z, a1.z);
        a1.w = fmaf(xv, w1.w, a1.w);
    }
    float dn = dis[row];
    half8 hv;
    hv[0] = (_Float16)(a0.x * dn);
    hv[1] = (_Float16)(a0.y * dn);
    hv[2] = (_Float16)(a0.z * dn);
    hv[3] = (_Float16)(a0.w * dn);
    hv[4] = (_Float16)(a1.x * dn);
    hv[5] = (_Float16)(a1.y * dn);
    hv[6] = (_Float16)(a1.z * dn);
    hv[7] = (_Float16)(a1.w * dn);
    ((half8*)H)[(size_t)row * (MOUT / 8) + c0 / 8] = hv;
}

// ---- final aggregate: M=32, fp32 out, no relu. lane-per-8-features,
// LPN=4, NPW=16, 4-edge unroll.
__global__ void k_aggregate32(const _Float16* __restrict__ h, const float* __restrict__ dis,
                              const int* __restrict__ row_start, const int* __restrict__ csr_src,
                              const float* __restrict__ b, float* __restrict__ out, int n) {
    constexpr int LPN = 4, NPW = 16;
    int gtid = blockIdx.x * blockDim.x + threadIdx.x;
    int wave = gtid >> 6;
    int lane = threadIdx.x & 63;
    int sub = lane / LPN, fl = lane % LPN;
    int node = wave * NPW + sub;
    if (node >= n) return;
    const half8* h8 = (const half8*)h;
    float acc[8];
#pragma unroll
    for (int j = 0; j < 8; ++j) acc[j] = 0.f;
    int e = row_start[node], e1 = row_start[node + 1];
    for (; e + 3 < e1; e += 4) {
        int s0 = csr_src[e], s1 = csr_src[e + 1];
        int s2 = csr_src[e + 2], s3 = csr_src[e + 3];
        half8 v0 = h8[(size_t)s0 * LPN + fl];
        half8 v1 = h8[(size_t)s1 * LPN + fl];
        half8 v2 = h8[(size_t)s2 * LPN + fl];
        half8 v3 = h8[(size_t)s3 * LPN + fl];
#pragma unroll
        for (int j = 0; j < 8; ++j)
            acc[j] += ((float)v0[j] + (float)v1[j]) + ((float)v2[j] + (float)v3[j]);
    }
    for (; e < e1; ++e) {
        int s0 = csr_src[e];
        half8 v0 = h8[(size_t)s0 * LPN + fl];
#pragma unroll
        for (int j = 0; j < 8; ++j) acc[j] += (float)v0[j];
    }
    float dn = dis[node];
    half8 hv = h8[(size_t)node * LPN + fl];
    float4 b0 = ((const float4*)b)[fl * 2];
    float4 b1 = ((const float4*)b)[fl * 2 + 1];
    float4* op = (float4*)(out + ((size_t)node * LPN + fl) * 8);
    op[0] = make_float4((acc[0] + (float)hv[0]) * dn + b0.x,
                        (acc[1] + (float)hv[1]) * dn + b0.y,
                        (acc[2] + (float)hv[2]) * dn + b0.z,
                        (acc[3] + (float)hv[3]) * dn + b0.w);
    op[1] = make_float4((acc[4] + (float)hv[4]) * dn + b1.x,
                        (acc[5] + (float)hv[5]) * dn + b1.y,
                        (acc[6] + (float)hv[6]) * dn + b1.z,
                        (acc[7] + (float)hv[7]) * dn + b1.w);
}

extern "C" void kernel_launch(void* const* d_in, const int* in_sizes, int n_in,
                              void* d_out, int out_size, void* d_ws, size_t ws_size,
                              hipStream_t stream) {
    const float* x   = (const float*)d_in[0];
    const int*   ei  = (const int*)d_in[1];
    const float* W1  = (const float*)d_in[2];
    const float* b1  = (const float*)d_in[3];
    const float* W2  = (const float*)d_in[4];
    const float* b2  = (const float*)d_in[5];
    const float* W3  = (const float*)d_in[6];
    const float* b3  = (const float*)d_in[7];
    float* out = (float*)d_out;

    const int N = in_sizes[0] / 64;
    const int E = in_sizes[1] / 2;
    const int* src = ei;
    const int* dst = ei + E;

    const int NBK = cdiv(N, 256);     // 391 buckets of 256 nodes
    const int NBA = cdiv(E, ACHUNK);  // 196 pass-A blocks
    const int nmat = NBK * NBA;       // 76636 scan elements

    // workspace layout
    const size_t Np = (size_t)((N + 63) / 64) * 64;
    char* p = (char*)d_ws;
    int*      counts_t = (int*)p;      p += (size_t)nmat * sizeof(int);
    int*      offsets  = (int*)p;      p += (size_t)nmat * sizeof(int);
    int*      bsum     = (int*)p;      p += 1024 * sizeof(int);
    int*      row_start= (int*)p;      p += (Np + 64) * sizeof(int);
    float*    dis      = (float*)p;    p += Np * sizeof(float);
    unsigned* bucketed = (unsigned*)p; p += (size_t)E * sizeof(unsigned);
    int*      csr_src  = (int*)p;      p += (size_t)E * sizeof(int);
    _Float16* bufA     = (_Float16*)p; p += Np * 64 * sizeof(_Float16);
    _Float16* bufB     = (_Float16*)p; p += Np * 64 * sizeof(_Float16);
    (void)ws_size;

    const int B = 256;
    const int nb = cdiv(nmat, SCAN_CHUNK);  // 75 <= 256

    // ---- CSR build: LDS counting sort, no global atomics ----
    k_bucket_hist<<<NBA, B, 0, stream>>>(dst, counts_t, NBK, NBA, E);
    k_scan_partial<<<nb, B, 0, stream>>>(counts_t, bsum, nmat);
    k_scan_final<<<nb, B, 0, stream>>>(counts_t, bsum, offsets, nb, nmat);
    k_bucket_scatter<<<NBA, B, 0, stream>>>(src, dst, offsets, bucketed, NBK, NBA, E);
    k_bucket_build<<<NBK, B, 0, stream>>>(bucketed, offsets, csr_src, row_start, dis,
                                          NBK, NBA, N, E);

    // ---- layer 1 gemm: x(64) @ W1 -> h1 (bufA) ----
    k_gemm_f<64, 64><<<cdiv(N, 32), B, 0, stream>>>(x, W1, dis, bufA, N);
    // ---- fused: agg(h1)+relu -> gemm W2 -> h2 (bufB) ----
    k_fused_agg_gemm<64><<<cdiv(N, 32), B, 0, stream>>>(
        bufA, dis, row_start, csr_src, b1, W2, bufB, N);
    // ---- fused: agg(h2)+relu -> gemm W3 -> h3 (bufA, 32-dim) ----
    k_fused_agg_gemm<32><<<cdiv(N, 32), B, 0, stream>>>(
        bufB, dis, row_start, csr_src, b2, W3, bufA, N);
    // ---- final aggregate: agg(h3) + b3 -> out (fp32) ----
    k_aggregate32<<<cdiv(cdiv(N, 16) * 64, B), B, 0, stream>>>(
        bufA, dis, row_start, csr_src, b3, out, N);
}